// Round 8
// baseline (30586.798 us; speedup 1.0000x reference)
//
#include <hip/hip_runtime.h>
#include <stdint.h>

#define T_LEN 4096
#define E_DIM 256
#define HH 256

typedef unsigned long long u64;

__device__ __forceinline__ float sigmoidf_(float x) {
    return __builtin_amdgcn_rcpf(1.0f + __expf(-x));
}
__device__ __forceinline__ float tanh_fast(float x) {
    float e = __expf(2.0f * x);
    return 1.0f - 2.0f * __builtin_amdgcn_rcpf(e + 1.0f);
}

// ---------------------------------------------------------------------------
// Kernel 1: embedding gather fused with input projection (unchanged).
// ---------------------------------------------------------------------------
__global__ __launch_bounds__(256) void proj_kernel(
    const int* __restrict__ sent, const float* __restrict__ embed,
    const float* __restrict__ Wih_f, const float* __restrict__ bih_f, const float* __restrict__ bhh_f,
    const float* __restrict__ Wih_b, const float* __restrict__ bih_b, const float* __restrict__ bhh_b,
    float* __restrict__ gates_f, float* __restrict__ gates_b)
{
    __shared__ float4 xt[16][64];
    const int tid = threadIdx.x;
    const int dir = blockIdx.y;
    const int t0  = blockIdx.x * 16;

    const float* Wih = dir ? Wih_b : Wih_f;
    const float* bih = dir ? bih_b : bih_f;
    const float* bhh = dir ? bhh_b : bhh_f;
    float* gates     = dir ? gates_b : gates_f;

    {
        int row = tid >> 4;
        int c   = tid & 15;
        const float4* src = (const float4*)(embed + (size_t)sent[t0 + row] * E_DIM);
        xt[row][c]      = src[c];
        xt[row][c + 16] = src[c + 16];
        xt[row][c + 32] = src[c + 32];
        xt[row][c + 48] = src[c + 48];
    }
    __syncthreads();

    float acc[4][16];
    #pragma unroll
    for (int ri = 0; ri < 4; ++ri)
        #pragma unroll
        for (int tt = 0; tt < 16; ++tt) acc[ri][tt] = 0.f;

    const float4* wrow0 = (const float4*)(Wih + (size_t)(0 * 256 + tid) * 256);
    const float4* wrow1 = (const float4*)(Wih + (size_t)(1 * 256 + tid) * 256);
    const float4* wrow2 = (const float4*)(Wih + (size_t)(2 * 256 + tid) * 256);
    const float4* wrow3 = (const float4*)(Wih + (size_t)(3 * 256 + tid) * 256);

    for (int k4 = 0; k4 < 64; ++k4) {
        float4 xv[16];
        #pragma unroll
        for (int tt = 0; tt < 16; ++tt) xv[tt] = xt[tt][k4];
        float4 w0 = wrow0[k4], w1 = wrow1[k4], w2 = wrow2[k4], w3 = wrow3[k4];
        #pragma unroll
        for (int tt = 0; tt < 16; ++tt) {
            acc[0][tt] += w0.x*xv[tt].x + w0.y*xv[tt].y + w0.z*xv[tt].z + w0.w*xv[tt].w;
            acc[1][tt] += w1.x*xv[tt].x + w1.y*xv[tt].y + w1.z*xv[tt].z + w1.w*xv[tt].w;
            acc[2][tt] += w2.x*xv[tt].x + w2.y*xv[tt].y + w2.z*xv[tt].z + w2.w*xv[tt].w;
            acc[3][tt] += w3.x*xv[tt].x + w3.y*xv[tt].y + w3.z*xv[tt].z + w3.w*xv[tt].w;
        }
    }

    #pragma unroll
    for (int ri = 0; ri < 4; ++ri) {
        int r = ri * 256 + tid;
        float b = bih[r] + bhh[r];
        #pragma unroll
        for (int tt = 0; tt < 16; ++tt)
            gates[(size_t)(t0 + tt) * 1024 + r] = acc[ri][tt] + b;
    }
}

// ---------------------------------------------------------------------------
// Kernel 2: BiLSTM recurrence — R5's proven sync shape (4-way gather per
// direction, 192 remote pollers fan-out-1 into LDS, one barrier per phase,
// own-slot-only init) with the two directions PAIRED inside each block.
// 4 blocks x 512 threads; block g owns j = g*64..g*64+63 for BOTH dirs
// (128+128 weight floats/thread, asm-pinned; at 2 waves/SIMD the unified
// VGPR+AGPR budget is ~1024/wave, ~300 used -> no spill).
// Step: poll-f / barrier / dot-f / publish-f  then  poll-b / barrier /
// dot-b / publish-b. Phase F's publish->visible RTT drains during phase B's
// compute and vice versa; if RTT < phase-compute (~800cy), each poll hits
// immediately and the step-pair is compute-bound.
// R6/R7 lessons honored: gather width stays 4, pollers/array stay 768,
// fan-out stays 1, init touches own slots only.
// ---------------------------------------------------------------------------
__global__ __launch_bounds__(512, 1) void lstm_kernel(
    const float* __restrict__ Whh_f, const float* __restrict__ Whh_b,
    const float* __restrict__ gates_f, const float* __restrict__ gates_b,
    const float* __restrict__ h0, const float* __restrict__ c0,
    float* __restrict__ h_out, u64* __restrict__ msg)
{
    const int g   = blockIdx.x;       // 0..3
    const int tid = threadIdx.x;
    const int s   = tid & 7;          // k-slice 0..7 (32 k each)
    const int jl  = tid >> 3;         // 0..63
    const int j   = g * 64 + jl;      // hidden index 0..255

    // wf/wb[gg*32 + i*4 + c] = Whh_d[(gg*256+j)*256 + s*32 + ((i+s)&7)*4 + c]
    // (rotation (i+s)&7 -> conflict-free LDS banks across the 8 s-groups)
    float wf[128], wb[128];
    #pragma unroll
    for (int gg = 0; gg < 4; ++gg) {
        const float4* rf = (const float4*)(Whh_f + (size_t)(gg * 256 + j) * 256 + s * 32);
        const float4* rb = (const float4*)(Whh_b + (size_t)(gg * 256 + j) * 256 + s * 32);
        #pragma unroll
        for (int i = 0; i < 8; ++i) {
            int idx = (i + s) & 7;
            float4 vf = rf[idx], vb = rb[idx];
            wf[gg*32 + i*4 + 0] = vf.x; wf[gg*32 + i*4 + 1] = vf.y;
            wf[gg*32 + i*4 + 2] = vf.z; wf[gg*32 + i*4 + 3] = vf.w;
            wb[gg*32 + i*4 + 0] = vb.x; wb[gg*32 + i*4 + 1] = vb.y;
            wb[gg*32 + i*4 + 2] = vb.z; wb[gg*32 + i*4 + 3] = vb.w;
        }
    }
    #pragma unroll
    for (int k = 0; k < 128; ++k) {
        asm volatile("" : "+v"(wf[k]));
        asm volatile("" : "+v"(wb[k]));
    }

    __shared__ __align__(16) float h_f[2][256];
    __shared__ __align__(16) float h_b[2][256];

    // init: OWN slots only (R7's all-slot init was an overwrite hazard)
    if (tid < 64) {
        int j0 = g * 64 + tid;
        float hf0 = h0[j0];
        float hb0 = h0[HH + j0];
        h_f[0][j0] = hf0;
        h_b[0][j0] = hb0;
        __hip_atomic_store(&msg[(0 * 2 + 0) * 256 + j0],
                           ((u64)1u << 32) | (u64)__float_as_uint(hf0),
                           __ATOMIC_RELAXED, __HIP_MEMORY_SCOPE_AGENT);
        __hip_atomic_store(&msg[(0 * 2 + 1) * 256 + j0],
                           ((u64)1u << 32) | (u64)__float_as_uint(hb0),
                           __ATOMIC_RELAXED, __HIP_MEMORY_SCOPE_AGENT);
    }
    float cf = 0.f, cb = 0.f;
    if (s == 0) { cf = c0[j]; cb = c0[HH + j]; }

    const bool remote = (tid < 256) && ((tid >> 6) != g);

    for (int t = 0; t < T_LEN; ++t) {
        const int tb = T_LEN - 1 - t;
        const unsigned want = (unsigned)(t + 1);
        const u64 newtag = ((u64)(unsigned)(t + 2)) << 32;
        const int par = t & 1, nxt = (t + 1) & 1;

        // finalists prefetch both directions' gate inputs (overlap the poll)
        float gf0 = 0.f, gf1 = 0.f, gf2 = 0.f, gf3 = 0.f;
        float gb0 = 0.f, gb1 = 0.f, gb2 = 0.f, gb3 = 0.f;
        if (s == 0) {
            const float* gpf = gates_f + (size_t)t  * 1024 + j;
            const float* gpb = gates_b + (size_t)tb * 1024 + j;
            gf0 = gpf[0]; gf1 = gpf[256]; gf2 = gpf[512]; gf3 = gpf[768];
            gb0 = gpb[0]; gb1 = gpb[256]; gb2 = gpb[512]; gb3 = gpb[768];
        }

        // ================= phase F =================
        if (remote) {
            u64* sp = &msg[(par * 2 + 0) * 256 + tid];
            u64 m;
            do {
                m = __hip_atomic_load(sp, __ATOMIC_RELAXED, __HIP_MEMORY_SCOPE_AGENT);
            } while ((unsigned)(m >> 32) != want);
            h_f[par][tid] = __uint_as_float((unsigned)m);
        }
        __syncthreads();

        {
            float p0 = 0.f, p1 = 0.f, p2 = 0.f, p3 = 0.f;
            const float4* hp = (const float4*)(&h_f[par][s * 32]);
            #pragma unroll
            for (int i = 0; i < 8; ++i) {
                float4 h4 = hp[(i + s) & 7];
                p0 += wf[i*4+0]*h4.x + wf[i*4+1]*h4.y + wf[i*4+2]*h4.z + wf[i*4+3]*h4.w;
                p1 += wf[32+i*4+0]*h4.x + wf[32+i*4+1]*h4.y + wf[32+i*4+2]*h4.z + wf[32+i*4+3]*h4.w;
                p2 += wf[64+i*4+0]*h4.x + wf[64+i*4+1]*h4.y + wf[64+i*4+2]*h4.z + wf[64+i*4+3]*h4.w;
                p3 += wf[96+i*4+0]*h4.x + wf[96+i*4+1]*h4.y + wf[96+i*4+2]*h4.z + wf[96+i*4+3]*h4.w;
            }
            #pragma unroll
            for (int mk = 1; mk <= 4; mk <<= 1) {
                p0 += __shfl_xor(p0, mk); p1 += __shfl_xor(p1, mk);
                p2 += __shfl_xor(p2, mk); p3 += __shfl_xor(p3, mk);
            }
            if (s == 0) {
                float iv = sigmoidf_(gf0 + p0);
                float fv = sigmoidf_(gf1 + p1);
                float gv = tanh_fast(gf2 + p2);
                float ov = sigmoidf_(gf3 + p3);
                cf = fv * cf + iv * gv;
                float h = ov * tanh_fast(cf);
                __hip_atomic_store(&msg[(nxt * 2 + 0) * 256 + j],
                                   newtag | (u64)__float_as_uint(h),
                                   __ATOMIC_RELAXED, __HIP_MEMORY_SCOPE_AGENT);
                h_f[nxt][j] = h;
                h_out[(size_t)t * 512 + j] = h;
            }
        }

        // ================= phase B =================
        // (phase F's publish drains to the coherence point during all of this)
        if (remote) {
            u64* sp = &msg[(par * 2 + 1) * 256 + tid];
            u64 m;
            do {
                m = __hip_atomic_load(sp, __ATOMIC_RELAXED, __HIP_MEMORY_SCOPE_AGENT);
            } while ((unsigned)(m >> 32) != want);
            h_b[par][tid] = __uint_as_float((unsigned)m);
        }
        __syncthreads();

        {
            float p0 = 0.f, p1 = 0.f, p2 = 0.f, p3 = 0.f;
            const float4* hp = (const float4*)(&h_b[par][s * 32]);
            #pragma unroll
            for (int i = 0; i < 8; ++i) {
                float4 h4 = hp[(i + s) & 7];
                p0 += wb[i*4+0]*h4.x + wb[i*4+1]*h4.y + wb[i*4+2]*h4.z + wb[i*4+3]*h4.w;
                p1 += wb[32+i*4+0]*h4.x + wb[32+i*4+1]*h4.y + wb[32+i*4+2]*h4.z + wb[32+i*4+3]*h4.w;
                p2 += wb[64+i*4+0]*h4.x + wb[64+i*4+1]*h4.y + wb[64+i*4+2]*h4.z + wb[64+i*4+3]*h4.w;
                p3 += wb[96+i*4+0]*h4.x + wb[96+i*4+1]*h4.y + wb[96+i*4+2]*h4.z + wb[96+i*4+3]*h4.w;
            }
            #pragma unroll
            for (int mk = 1; mk <= 4; mk <<= 1) {
                p0 += __shfl_xor(p0, mk); p1 += __shfl_xor(p1, mk);
                p2 += __shfl_xor(p2, mk); p3 += __shfl_xor(p3, mk);
            }
            if (s == 0) {
                float iv = sigmoidf_(gb0 + p0);
                float fv = sigmoidf_(gb1 + p1);
                float gv = tanh_fast(gb2 + p2);
                float ov = sigmoidf_(gb3 + p3);
                cb = fv * cb + iv * gv;
                float h = ov * tanh_fast(cb);
                __hip_atomic_store(&msg[(nxt * 2 + 1) * 256 + j],
                                   newtag | (u64)__float_as_uint(h),
                                   __ATOMIC_RELAXED, __HIP_MEMORY_SCOPE_AGENT);
                h_b[nxt][j] = h;
                h_out[(size_t)tb * 512 + HH + j] = h;
            }
        }
        // LDS safety: dot reads of parity p at step t end before barrier(B,t);
        // pollers next write parity p at step t+2 after barrier(F,t+2) or at
        // least after barrier(B,t+1) > barrier(B,t). ABA on msg: per
        // direction identical to R5 (tag t+2 stored only after this block's
        // poll saw tag t+1 from every remote, which sits behind their
        // consumption of tag t + a barrier).
    }
}

// ---------------------------------------------------------------------------
// Kernel 3: feats[t][k] = dot(h_out[t,:], W_out[k,:]) + b_out[k]
// ---------------------------------------------------------------------------
__global__ __launch_bounds__(64) void feats_kernel(
    const float* __restrict__ h_out, const float* __restrict__ W_out,
    const float* __restrict__ b_out, float* __restrict__ feats)
{
    const int t = blockIdx.x;
    const int lane = threadIdx.x;
    const int k = lane >> 1, half = lane & 1;
    const float4* hv = (const float4*)(h_out + (size_t)t * 512 + half * 256);
    const float4* wv = (const float4*)(W_out + (size_t)k * 512 + half * 256);
    float p = 0.f;
    #pragma unroll 16
    for (int i = 0; i < 64; ++i) {
        float4 a = hv[i], b = wv[i];
        p += a.x*b.x + a.y*b.y + a.z*b.z + a.w*b.w;
    }
    p += __shfl_xor(p, 1);
    if (half == 0) feats[t * 32 + k] = p + b_out[k];
}

// ---------------------------------------------------------------------------
// Kernel 4: Viterbi (R4 version — proven).
// ---------------------------------------------------------------------------
#define VT_CHUNK 128
__global__ __launch_bounds__(64) void viterbi_kernel(
    const float* __restrict__ feats, const float* __restrict__ trans,
    float* __restrict__ out)
{
    extern __shared__ unsigned char dynls[];
    unsigned char* ixs = dynls;                       // (T-1)*32 = 131040 B
    float* fchunk = (float*)(dynls + 131072);         // VT_CHUNK*32 floats
    __shared__ float fin[32];

    const int lane = threadIdx.x;
    const int j = lane >> 1, ih = lane & 1;

    float ttr[16];
    #pragma unroll
    for (int q = 0; q < 16; ++q) ttr[q] = trans[(ih * 16 + q) * 32 + j];

    float alpha = 0.f;

    for (int cs = 0; cs < T_LEN; cs += VT_CHUNK) {
        const float4* src = (const float4*)(feats + (size_t)cs * 32);
        float4* dst = (float4*)fchunk;
        #pragma unroll
        for (int i = 0; i < 16; ++i) dst[lane + 64 * i] = src[lane + 64 * i];
        __syncthreads();

        int tbeg = cs;
        if (cs == 0) { alpha = fchunk[j]; tbeg = 1; }

        for (int t = tbeg; t < cs + VT_CHUNK; ++t) {
            float obs = fchunk[(t - cs) * 32 + j];
            float v[16]; int ix[16];
            #pragma unroll
            for (int q = 0; q < 16; ++q) {
                int i = ih * 16 + q;
                v[q] = (__shfl(alpha, 2 * i) + ttr[q]) + obs;
                ix[q] = i;
            }
            #pragma unroll
            for (int st = 8; st >= 1; st >>= 1)
                #pragma unroll
                for (int q = 0; q < 8; ++q)
                    if (q < st && v[q + st] > v[q]) { v[q] = v[q + st]; ix[q] = ix[q + st]; }
            float best = v[0]; int barg = ix[0];

            float ob = __shfl_xor(best, 1); int oa = __shfl_xor(barg, 1);
            float m0 = ih ? ob : best; int a0 = ih ? oa : barg;
            float m1 = ih ? best : ob; int a1 = ih ? barg : oa;
            float m = m0; int a = a0;
            if (m1 > m0) { m = m1; a = a1; }
            if (ih == 0) ixs[(t - 1) * 32 + j] = (unsigned char)a;
            alpha = m;
        }
        __syncthreads();
    }

    if (ih == 0) fin[j] = alpha;
    __syncthreads();

    if (lane == 0) {
        float sc = fin[0]; int cur = 0;
        for (int q = 1; q < 32; ++q)
            if (fin[q] > sc) { sc = fin[q]; cur = q; }
        out[T_LEN] = sc;
        out[T_LEN - 1] = (float)cur;
        for (int t = T_LEN - 2; t >= 0; --t) {
            cur = ixs[t * 32 + cur];
            out[t] = (float)cur;
        }
    }
}

// ---------------------------------------------------------------------------
extern "C" void kernel_launch(void* const* d_in, const int* in_sizes, int n_in,
                              void* d_out, int out_size, void* d_ws, size_t ws_size,
                              hipStream_t stream) {
    const int*   sent  = (const int*)d_in[0];
    const float* embed = (const float*)d_in[1];
    const float* Wih_f = (const float*)d_in[2];
    const float* Whh_f = (const float*)d_in[3];
    const float* bih_f = (const float*)d_in[4];
    const float* bhh_f = (const float*)d_in[5];
    const float* Wih_b = (const float*)d_in[6];
    const float* Whh_b = (const float*)d_in[7];
    const float* bih_b = (const float*)d_in[8];
    const float* bhh_b = (const float*)d_in[9];
    const float* h0    = (const float*)d_in[10];
    const float* c0    = (const float*)d_in[11];
    const float* W_out = (const float*)d_in[12];
    const float* b_out = (const float*)d_in[13];
    const float* trans = (const float*)d_in[14];
    float* out = (float*)d_out;

    float* gates_f = (float*)d_ws;                              // T*1024
    float* gates_b = gates_f + (size_t)T_LEN * 1024;            // T*1024
    float* h_out   = gates_b + (size_t)T_LEN * 1024;            // T*512
    float* feats   = h_out   + (size_t)T_LEN * 512;             // T*32
    u64*   msg     = (u64*)(feats + (size_t)T_LEN * 32);        // 2*2*256

    dim3 gproj(T_LEN / 16, 2);
    proj_kernel<<<gproj, 256, 0, stream>>>(sent, embed,
        Wih_f, bih_f, bhh_f, Wih_b, bih_b, bhh_b, gates_f, gates_b);

    lstm_kernel<<<4, 512, 0, stream>>>(Whh_f, Whh_b, gates_f, gates_b,
                                       h0, c0, h_out, msg);

    feats_kernel<<<T_LEN, 64, 0, stream>>>(h_out, W_out, b_out, feats);

    hipFuncSetAttribute((const void*)viterbi_kernel,
                        hipFuncAttributeMaxDynamicSharedMemorySize, 147456);
    viterbi_kernel<<<1, 64, 147456, stream>>>(feats, trans, out);
}

// Round 9
// 7761.610 us; speedup vs baseline: 3.9408x; 3.9408x over previous
//
#include <hip/hip_runtime.h>
#include <stdint.h>

#define T_LEN 4096
#define E_DIM 256
#define HH 256
#define MSTRIDE 16   // u64s per mailbox slot: 1 slot per 128B line

typedef unsigned long long u64;

__device__ __forceinline__ float sigmoidf_(float x) {
    return __builtin_amdgcn_rcpf(1.0f + __expf(-x));
}
__device__ __forceinline__ float tanh_fast(float x) {
    float e = __expf(2.0f * x);
    return 1.0f - 2.0f * __builtin_amdgcn_rcpf(e + 1.0f);
}

// ---------------------------------------------------------------------------
// Kernel 1: embedding gather fused with input projection (unchanged).
// ---------------------------------------------------------------------------
__global__ __launch_bounds__(256) void proj_kernel(
    const int* __restrict__ sent, const float* __restrict__ embed,
    const float* __restrict__ Wih_f, const float* __restrict__ bih_f, const float* __restrict__ bhh_f,
    const float* __restrict__ Wih_b, const float* __restrict__ bih_b, const float* __restrict__ bhh_b,
    float* __restrict__ gates_f, float* __restrict__ gates_b)
{
    __shared__ float4 xt[16][64];
    const int tid = threadIdx.x;
    const int dir = blockIdx.y;
    const int t0  = blockIdx.x * 16;

    const float* Wih = dir ? Wih_b : Wih_f;
    const float* bih = dir ? bih_b : bih_f;
    const float* bhh = dir ? bhh_b : bhh_f;
    float* gates     = dir ? gates_b : gates_f;

    {
        int row = tid >> 4;
        int c   = tid & 15;
        const float4* src = (const float4*)(embed + (size_t)sent[t0 + row] * E_DIM);
        xt[row][c]      = src[c];
        xt[row][c + 16] = src[c + 16];
        xt[row][c + 32] = src[c + 32];
        xt[row][c + 48] = src[c + 48];
    }
    __syncthreads();

    float acc[4][16];
    #pragma unroll
    for (int ri = 0; ri < 4; ++ri)
        #pragma unroll
        for (int tt = 0; tt < 16; ++tt) acc[ri][tt] = 0.f;

    const float4* wrow0 = (const float4*)(Wih + (size_t)(0 * 256 + tid) * 256);
    const float4* wrow1 = (const float4*)(Wih + (size_t)(1 * 256 + tid) * 256);
    const float4* wrow2 = (const float4*)(Wih + (size_t)(2 * 256 + tid) * 256);
    const float4* wrow3 = (const float4*)(Wih + (size_t)(3 * 256 + tid) * 256);

    for (int k4 = 0; k4 < 64; ++k4) {
        float4 xv[16];
        #pragma unroll
        for (int tt = 0; tt < 16; ++tt) xv[tt] = xt[tt][k4];
        float4 w0 = wrow0[k4], w1 = wrow1[k4], w2 = wrow2[k4], w3 = wrow3[k4];
        #pragma unroll
        for (int tt = 0; tt < 16; ++tt) {
            acc[0][tt] += w0.x*xv[tt].x + w0.y*xv[tt].y + w0.z*xv[tt].z + w0.w*xv[tt].w;
            acc[1][tt] += w1.x*xv[tt].x + w1.y*xv[tt].y + w1.z*xv[tt].z + w1.w*xv[tt].w;
            acc[2][tt] += w2.x*xv[tt].x + w2.y*xv[tt].y + w2.z*xv[tt].z + w2.w*xv[tt].w;
            acc[3][tt] += w3.x*xv[tt].x + w3.y*xv[tt].y + w3.z*xv[tt].z + w3.w*xv[tt].w;
        }
    }

    #pragma unroll
    for (int ri = 0; ri < 4; ++ri) {
        int r = ri * 256 + tid;
        float b = bih[r] + bhh[r];
        #pragma unroll
        for (int tt = 0; tt < 16; ++tt)
            gates[(size_t)(t0 + tt) * 1024 + r] = acc[ri][tt] + b;
    }
}

// ---------------------------------------------------------------------------
// Kernel 2: BiLSTM recurrence — EXACT R5 structure (best measured: 5003us;
// 8 working blocks of 512 thr, one direction each, 4-way gather, 192
// fan-out-1 pollers into LDS, one barrier/step, asm-pinned weights) with two
// anti-contention changes targeting the ~2350cy publish->visible latency:
//   1. mailbox slots padded to one per 128B line (was 16 slots/line with
//      ~48 spinners + 16 producers per line; R6 showed spin reads delay
//      store visibility)
//   2. s_sleep(1) backoff in the spin loop (~5x lower poll-issue rate)
// R6/R7/R8 lesson: do NOT pair directions in one block (3/3 regressions).
// ---------------------------------------------------------------------------
__global__ __launch_bounds__(512, 1) void lstm_kernel(
    const float* __restrict__ Whh_f, const float* __restrict__ Whh_b,
    const float* __restrict__ gates_f, const float* __restrict__ gates_b,
    const float* __restrict__ h0, const float* __restrict__ c0,
    float* __restrict__ h_out, u64* __restrict__ msg)
{
    const int xcd  = blockIdx.x & 7;
    const int slot = blockIdx.x >> 3;
    if (xcd > 1 || slot > 3) return;   // filler blocks exit
    const int dir = xcd;
    const int g   = slot;

    const int tid = threadIdx.x;
    const int s   = tid & 7;           // k-slice 0..7 (32 k each)
    const int jl  = tid >> 3;          // 0..63
    const int j   = g * 64 + jl;       // hidden index 0..255

    const float* Whh   = dir ? Whh_b : Whh_f;
    const float* gates = dir ? gates_b : gates_f;

    // w[gg*32 + i*4 + c] = Whh[(gg*256+j)*256 + s*32 + ((i+s)&7)*4 + c]
    float w[128];
    #pragma unroll
    for (int gg = 0; gg < 4; ++gg) {
        const float4* row = (const float4*)(Whh + (size_t)(gg * 256 + j) * 256 + s * 32);
        #pragma unroll
        for (int i = 0; i < 8; ++i) {
            float4 v = row[(i + s) & 7];
            w[gg * 32 + i * 4 + 0] = v.x;
            w[gg * 32 + i * 4 + 1] = v.y;
            w[gg * 32 + i * 4 + 2] = v.z;
            w[gg * 32 + i * 4 + 3] = v.w;
        }
    }
    #pragma unroll
    for (int k = 0; k < 128; ++k)
        asm volatile("" : "+v"(w[k]));

    __shared__ __align__(16) float h_lds[2][256];

    float c = 0.f;
    if (tid < 64) {
        int j0 = g * 64 + tid;
        float h = h0[dir * HH + j0];
        h_lds[0][j0] = h;
        __hip_atomic_store(&msg[(size_t)((0 * 2 + dir) * 256 + j0) * MSTRIDE],
                           ((u64)1u << 32) | (u64)__float_as_uint(h),
                           __ATOMIC_RELAXED, __HIP_MEMORY_SCOPE_AGENT);
    }
    if (s == 0) c = c0[dir * HH + j];

    for (int t = 0; t < T_LEN; ++t) {
        const int tf = dir ? (T_LEN - 1 - t) : t;

        // finalists prefetch gate inputs (overlaps the poll)
        float gin0 = 0.f, gin1 = 0.f, gin2 = 0.f, gin3 = 0.f;
        if (s == 0) {
            const float* gp = gates + (size_t)tf * 1024 + j;
            gin0 = gp[0]; gin1 = gp[256]; gin2 = gp[512]; gin3 = gp[768];
        }

        // poll the 192 remote h values, fan-out 1, into LDS; backoff spin
        if (tid < 256 && (tid >> 6) != g) {
            u64* sp = &msg[(size_t)(((t & 1) * 2 + dir) * 256 + tid) * MSTRIDE];
            const unsigned want = (unsigned)(t + 1);
            u64 m = __hip_atomic_load(sp, __ATOMIC_RELAXED, __HIP_MEMORY_SCOPE_AGENT);
            while ((unsigned)(m >> 32) != want) {
                __builtin_amdgcn_s_sleep(1);
                m = __hip_atomic_load(sp, __ATOMIC_RELAXED, __HIP_MEMORY_SCOPE_AGENT);
            }
            h_lds[t & 1][tid] = __uint_as_float((unsigned)m);
        }
        __syncthreads();   // the ONLY barrier per step

        // 4-gate partial dot over this thread's 32-k slice
        float p0 = 0.f, p1 = 0.f, p2 = 0.f, p3 = 0.f;
        const float4* hp = (const float4*)(&h_lds[t & 1][s * 32]);
        #pragma unroll
        for (int i = 0; i < 8; ++i) {
            float4 h4 = hp[(i + s) & 7];
            p0 += w[i*4+0]*h4.x + w[i*4+1]*h4.y + w[i*4+2]*h4.z + w[i*4+3]*h4.w;
            p1 += w[32+i*4+0]*h4.x + w[32+i*4+1]*h4.y + w[32+i*4+2]*h4.z + w[32+i*4+3]*h4.w;
            p2 += w[64+i*4+0]*h4.x + w[64+i*4+1]*h4.y + w[64+i*4+2]*h4.z + w[64+i*4+3]*h4.w;
            p3 += w[96+i*4+0]*h4.x + w[96+i*4+1]*h4.y + w[96+i*4+2]*h4.z + w[96+i*4+3]*h4.w;
        }

        // butterfly reduce across the 8 k-slices (lane bits 0..2)
        #pragma unroll
        for (int m = 1; m <= 4; m <<= 1) {
            p0 += __shfl_xor(p0, m);
            p1 += __shfl_xor(p1, m);
            p2 += __shfl_xor(p2, m);
            p3 += __shfl_xor(p3, m);
        }

        if (s == 0) {
            float iv = sigmoidf_(gin0 + p0);
            float fv = sigmoidf_(gin1 + p1);
            float gv = tanh_fast(gin2 + p2);
            float ov = sigmoidf_(gin3 + p3);
            c = fv * c + iv * gv;
            float h = ov * tanh_fast(c);
            // publish: msg first (critical path), then local LDS, then h_out
            __hip_atomic_store(&msg[(size_t)((((t + 1) & 1) * 2 + dir) * 256 + j) * MSTRIDE],
                               (((u64)(unsigned)(t + 2)) << 32) | (u64)__float_as_uint(h),
                               __ATOMIC_RELAXED, __HIP_MEMORY_SCOPE_AGENT);
            h_lds[(t + 1) & 1][j] = h;
            h_out[(size_t)tf * 512 + dir * HH + j] = h;
        }
        // ABA-safe: tag t+2 overwrites a slot only after this block's poll
        // saw tag t+1 from every remote block, which sits behind their
        // consumption of tag t + a barrier.
    }
}

// ---------------------------------------------------------------------------
// Kernel 3: feats[t][k] = dot(h_out[t,:], W_out[k,:]) + b_out[k]
// ---------------------------------------------------------------------------
__global__ __launch_bounds__(64) void feats_kernel(
    const float* __restrict__ h_out, const float* __restrict__ W_out,
    const float* __restrict__ b_out, float* __restrict__ feats)
{
    const int t = blockIdx.x;
    const int lane = threadIdx.x;
    const int k = lane >> 1, half = lane & 1;
    const float4* hv = (const float4*)(h_out + (size_t)t * 512 + half * 256);
    const float4* wv = (const float4*)(W_out + (size_t)k * 512 + half * 256);
    float p = 0.f;
    #pragma unroll 16
    for (int i = 0; i < 64; ++i) {
        float4 a = hv[i], b = wv[i];
        p += a.x*b.x + a.y*b.y + a.z*b.z + a.w*b.w;
    }
    p += __shfl_xor(p, 1);
    if (half == 0) feats[t * 32 + k] = p + b_out[k];
}

// ---------------------------------------------------------------------------
// Kernel 4: Viterbi (R4 version — proven).
// ---------------------------------------------------------------------------
#define VT_CHUNK 128
__global__ __launch_bounds__(64) void viterbi_kernel(
    const float* __restrict__ feats, const float* __restrict__ trans,
    float* __restrict__ out)
{
    extern __shared__ unsigned char dynls[];
    unsigned char* ixs = dynls;                       // (T-1)*32 = 131040 B
    float* fchunk = (float*)(dynls + 131072);         // VT_CHUNK*32 floats
    __shared__ float fin[32];

    const int lane = threadIdx.x;
    const int j = lane >> 1, ih = lane & 1;

    float ttr[16];
    #pragma unroll
    for (int q = 0; q < 16; ++q) ttr[q] = trans[(ih * 16 + q) * 32 + j];

    float alpha = 0.f;

    for (int cs = 0; cs < T_LEN; cs += VT_CHUNK) {
        const float4* src = (const float4*)(feats + (size_t)cs * 32);
        float4* dst = (float4*)fchunk;
        #pragma unroll
        for (int i = 0; i < 16; ++i) dst[lane + 64 * i] = src[lane + 64 * i];
        __syncthreads();

        int tbeg = cs;
        if (cs == 0) { alpha = fchunk[j]; tbeg = 1; }

        for (int t = tbeg; t < cs + VT_CHUNK; ++t) {
            float obs = fchunk[(t - cs) * 32 + j];
            float v[16]; int ix[16];
            #pragma unroll
            for (int q = 0; q < 16; ++q) {
                int i = ih * 16 + q;
                v[q] = (__shfl(alpha, 2 * i) + ttr[q]) + obs;
                ix[q] = i;
            }
            #pragma unroll
            for (int st = 8; st >= 1; st >>= 1)
                #pragma unroll
                for (int q = 0; q < 8; ++q)
                    if (q < st && v[q + st] > v[q]) { v[q] = v[q + st]; ix[q] = ix[q + st]; }
            float best = v[0]; int barg = ix[0];

            float ob = __shfl_xor(best, 1); int oa = __shfl_xor(barg, 1);
            float m0 = ih ? ob : best; int a0 = ih ? oa : barg;
            float m1 = ih ? best : ob; int a1 = ih ? barg : oa;
            float m = m0; int a = a0;
            if (m1 > m0) { m = m1; a = a1; }
            if (ih == 0) ixs[(t - 1) * 32 + j] = (unsigned char)a;
            alpha = m;
        }
        __syncthreads();
    }

    if (ih == 0) fin[j] = alpha;
    __syncthreads();

    if (lane == 0) {
        float sc = fin[0]; int cur = 0;
        for (int q = 1; q < 32; ++q)
            if (fin[q] > sc) { sc = fin[q]; cur = q; }
        out[T_LEN] = sc;
        out[T_LEN - 1] = (float)cur;
        for (int t = T_LEN - 2; t >= 0; --t) {
            cur = ixs[t * 32 + cur];
            out[t] = (float)cur;
        }
    }
}

// ---------------------------------------------------------------------------
extern "C" void kernel_launch(void* const* d_in, const int* in_sizes, int n_in,
                              void* d_out, int out_size, void* d_ws, size_t ws_size,
                              hipStream_t stream) {
    const int*   sent  = (const int*)d_in[0];
    const float* embed = (const float*)d_in[1];
    const float* Wih_f = (const float*)d_in[2];
    const float* Whh_f = (const float*)d_in[3];
    const float* bih_f = (const float*)d_in[4];
    const float* bhh_f = (const float*)d_in[5];
    const float* Wih_b = (const float*)d_in[6];
    const float* Whh_b = (const float*)d_in[7];
    const float* bih_b = (const float*)d_in[8];
    const float* bhh_b = (const float*)d_in[9];
    const float* h0    = (const float*)d_in[10];
    const float* c0    = (const float*)d_in[11];
    const float* W_out = (const float*)d_in[12];
    const float* b_out = (const float*)d_in[13];
    const float* trans = (const float*)d_in[14];
    float* out = (float*)d_out;

    float* gates_f = (float*)d_ws;                              // T*1024
    float* gates_b = gates_f + (size_t)T_LEN * 1024;            // T*1024
    float* h_out   = gates_b + (size_t)T_LEN * 1024;            // T*512
    float* feats   = h_out   + (size_t)T_LEN * 512;             // T*32
    u64*   msg     = (u64*)(feats + (size_t)T_LEN * 32);        // 1024*16 u64 = 128KB

    dim3 gproj(T_LEN / 16, 2);
    proj_kernel<<<gproj, 256, 0, stream>>>(sent, embed,
        Wih_f, bih_f, bhh_f, Wih_b, bih_b, bhh_b, gates_f, gates_b);

    lstm_kernel<<<64, 512, 0, stream>>>(Whh_f, Whh_b, gates_f, gates_b,
                                        h0, c0, h_out, msg);

    feats_kernel<<<T_LEN, 64, 0, stream>>>(h_out, W_out, b_out, feats);

    hipFuncSetAttribute((const void*)viterbi_kernel,
                        hipFuncAttributeMaxDynamicSharedMemorySize, 147456);
    viterbi_kernel<<<1, 64, 147456, stream>>>(feats, trans, out);
}